// Round 7
// baseline (571.930 us; speedup 1.0000x reference)
//
#include <hip/hip_runtime.h>
#include <hip/hip_bf16.h>
#include <math.h>

#define BNROWS (4096*32)   // 131072
#define RB     64          // rows per block = 2 SVGD states
#define LN32   3.4657359027997265f

typedef __attribute__((ext_vector_type(8))) short bf16x8;
typedef __attribute__((ext_vector_type(4))) float f32x4;

static __device__ __forceinline__ ushort f2bf(float x) {
    union { __hip_bfloat16 h; ushort u; } cv;
    cv.h = __float2bfloat16(x);
    return cv.u;
}

// ---------------------------------------------------------------------------
__global__ void obs_to_bf16(const float* __restrict__ obs,
                            ushort* __restrict__ obs_bf) {
    size_t i = ((size_t)blockIdx.x * 256 + threadIdx.x) * 4;
    float4 v = *(const float4*)&obs[i];
    ushort4 o;
    o.x = f2bf(v.x); o.y = f2bf(v.y); o.z = f2bf(v.z); o.w = f2bf(v.w);
    *(ushort4*)&obs_bf[i] = o;
}

// ---------------------------------------------------------------------------
// Pack weights into MFMA fragment order (lane-contiguous 16B loads).
// Lane (q,m): element j -> W[k = c*32 + q*8 + j][n = tile*16 + m].
__global__ void prep_pack(const float* __restrict__ w1,
                          const float* __restrict__ w2,
                          ushort* __restrict__ pB1, ushort* __restrict__ pB2,
                          ushort* __restrict__ pB3, ushort* __restrict__ pB4) {
    int g = blockIdx.x * 256 + threadIdx.x;   // 19968 total
    ushort out[8];
    ushort* dst;
    if (g < 3072) {
        int lane = g & 63, gc = g >> 6;
        int t = gc / 3, c = gc % 3;
        int m = lane & 15, q = lane >> 4, n = t * 16 + m;
        #pragma unroll
        for (int j = 0; j < 8; ++j) {
            int k = c * 32 + q * 8 + j;
            out[j] = f2bf((k < 80) ? w1[k * 256 + n] : 0.f);
        }
        dst = &pB1[g * 8];
    } else if (g < 11264) {
        int gg = g - 3072;
        int lane = gg & 63, gc = gg >> 6;
        int t = gc >> 3, c = gc & 7;
        int m = lane & 15, q = lane >> 4, n = t * 16 + m;
        #pragma unroll
        for (int j = 0; j < 8; ++j)
            out[j] = f2bf(w2[(c * 32 + q * 8 + j) * 256 + n]);
        dst = &pB2[gg * 8];
    } else if (g < 19456) {
        int gg = g - 11264;
        int lane = gg & 63, gc = gg >> 6;
        int t = gc >> 3, c = gc & 7;
        int m = lane & 15, q = lane >> 4;
        #pragma unroll
        for (int j = 0; j < 8; ++j)
            out[j] = f2bf(w2[(t * 16 + m) * 256 + c * 32 + q * 8 + j]);
        dst = &pB3[gg * 8];
    } else if (g < 19968) {
        int gg = g - 19456;
        int lane = gg & 63, c = gg >> 6;
        int m = lane & 15, q = lane >> 4;
        #pragma unroll
        for (int j = 0; j < 8; ++j)
            out[j] = f2bf(w1[(64 + m) * 256 + c * 32 + q * 8 + j]);
        dst = &pB4[gg * 8];
    } else return;
    *(uint4*)dst = *(uint4*)out;
}

// ---------------------------------------------------------------------------
// ONE SVGD step, fully fused: bf16-MFMA critic fwd+bwd (swapped operands,
// round-6 structure) + inline SVGD tail (2 states/block, round-5-proven code).
// Single step per kernel => MFMA accs die before svgd regs are born (the
// 3-step mega-kernel of round 5 spilled 2.1 GB; this must not re-merge steps).
// LDS overlays: B0 (h1/dz2/dz1) -> D2/KM/P/hist after phase E;
//               B1s (h0)        -> XA/SS after phase B.
// Plain __launch_bounds__(256): min-wave bounds caused scratch spill (r3/r4/r5).
__global__ __launch_bounds__(256) void mlp_svgd(
    const ushort* __restrict__ obs_bf,  // [BN,64] bf16
    const float* __restrict__ a_in,     // [BN,16]
    const float* __restrict__ b1,       // [256]
    const float* __restrict__ b2,       // [256]
    const float* __restrict__ w3,       // [256]
    const float* __restrict__ b3,       // [1]
    const ushort* __restrict__ pB1, const ushort* __restrict__ pB2,
    const ushort* __restrict__ pB3, const ushort* __restrict__ pB4,
    const float* __restrict__ logp_in,  // [BN] (ignored if first)
    float* __restrict__ logp_out,       // [BN]
    float* __restrict__ a_next,         // [BN,16]
    float* __restrict__ qout,           // [BN]
    int first)
{
    __shared__ __align__(16) char B0raw[RB * 264 * 2];  // 33792 B
    __shared__ __align__(16) char B1raw[RB * 104 * 2];  // 13312 B
    __shared__ float qpart[4][RB];
    __shared__ float bias1[256], bias2[256], w3s[256];
    __shared__ float medsh[2];
    __shared__ int   bbin[2], bexcl[2], wsumS[2][2], redc[2][2];
    __shared__ unsigned redm[2][2];

    ushort* B0  = (ushort*)B0raw;
    ushort* B1s = (ushort*)B1raw;
    float*  XA  = (float*)B1raw;          // [64*17] after phase B
    float*  SS  = XA + RB * 17;           // [64*17]
    float*  D2a = (float*)B0raw;          // [2][1056] after phase E
    float*  KMa = D2a + 2112;
    float*  PPa = KMa + 2112;
    int*    hista = (int*)(PPa + 2112);   // [2][256] -> ends 27392 < 33792

    const int tid  = threadIdx.x;
    const int row0 = blockIdx.x * RB;

    // ---- Phase A: stage h0 = [obs_bf16 | a->bf16 | 0pad] at stride 104
    for (int u = tid; u < 512; u += 256) {
        int r = u >> 3, ch = u & 7;
        *(uint4*)&B1s[r * 104 + ch * 8] =
            *(const uint4*)&obs_bf[(size_t)(row0 + r) * 64 + ch * 8];
    }
    {
        int r = tid >> 2, d0 = (tid & 3) * 4;
        float4 av = *(const float4*)&a_in[(size_t)(row0 + r) * 16 + d0];
        ushort4 pv;
        pv.x = f2bf(av.x); pv.y = f2bf(av.y); pv.z = f2bf(av.z); pv.w = f2bf(av.w);
        *(ushort4*)&B1s[r * 104 + 64 + d0] = pv;
        ushort4 zv; zv.x = zv.y = zv.z = zv.w = 0;
        *(ushort4*)&B1s[r * 104 + 80 + d0] = zv;
    }
    bias1[tid] = b1[tid]; bias2[tid] = b2[tid]; w3s[tid] = w3[tid];
    __syncthreads();                                       // (1)

    const int lane = tid & 63;
    const int w    = tid >> 6;
    const int m    = lane & 15;
    const int q    = lane >> 4;
    const int qk   = q * 8;

    f32x4 acc[4][4];                 // [row-tile][col-tile], transposed product
    unsigned long long relumask = 0ULL;

    // ---- Phase B: z1 = h0 @ w1 (+b1) ; relu -> B0 ; mask -> regs
    #pragma unroll
    for (int tc = 0; tc < 4; ++tc)
        #pragma unroll
        for (int rt = 0; rt < 4; ++rt) acc[rt][tc] = (f32x4){0.f, 0.f, 0.f, 0.f};
    for (int c = 0; c < 3; ++c) {
        bf16x8 af[4];
        #pragma unroll
        for (int rt = 0; rt < 4; ++rt)
            af[rt] = *(const bf16x8*)&B1s[(rt * 16 + m) * 104 + c * 32 + qk];
        #pragma unroll
        for (int tc = 0; tc < 4; ++tc) {
            bf16x8 wfr = *(const bf16x8*)&pB1[(((w * 4 + tc) * 3 + c) * 64 + lane) * 8];
            #pragma unroll
            for (int rt = 0; rt < 4; ++rt)
                acc[rt][tc] = __builtin_amdgcn_mfma_f32_16x16x32_bf16(wfr, af[rt], acc[rt][tc], 0, 0, 0);
        }
    }
    #pragma unroll
    for (int tc = 0; tc < 4; ++tc) {
        const float4 bv = *(const float4*)&bias1[(w * 4 + tc) * 16 + q * 4];
        const float bva[4] = {bv.x, bv.y, bv.z, bv.w};
        #pragma unroll
        for (int rt = 0; rt < 4; ++rt) {
            ushort4 pk;
            float z0 = acc[rt][tc][0] + bva[0];
            float z1 = acc[rt][tc][1] + bva[1];
            float z2 = acc[rt][tc][2] + bva[2];
            float z3 = acc[rt][tc][3] + bva[3];
            if (z0 > 0.f) relumask |= 1ULL << (rt * 16 + tc * 4 + 0);
            if (z1 > 0.f) relumask |= 1ULL << (rt * 16 + tc * 4 + 1);
            if (z2 > 0.f) relumask |= 1ULL << (rt * 16 + tc * 4 + 2);
            if (z3 > 0.f) relumask |= 1ULL << (rt * 16 + tc * 4 + 3);
            pk.x = f2bf(fmaxf(z0, 0.f)); pk.y = f2bf(fmaxf(z1, 0.f));
            pk.z = f2bf(fmaxf(z2, 0.f)); pk.w = f2bf(fmaxf(z3, 0.f));
            *(ushort4*)&B0[(rt * 16 + m) * 264 + (w * 4 + tc) * 16 + q * 4] = pk;
        }
    }
    __syncthreads();                                       // (2) h0 dead

    // XA <- exact fp32 actions (overlays dead h0 region; consumed by tail)
    {
        int r = tid >> 2, d0 = (tid & 3) * 4;
        float4 av = *(const float4*)&a_in[(size_t)(row0 + r) * 16 + d0];
        XA[r * 17 + d0 + 0] = av.x; XA[r * 17 + d0 + 1] = av.y;
        XA[r * 17 + d0 + 2] = av.z; XA[r * 17 + d0 + 3] = av.w;
    }

    // ---- Phase C: z2 = h1 @ w2 (+b2) ; q partials ; dz2 -> B0
    #pragma unroll
    for (int tc = 0; tc < 4; ++tc)
        #pragma unroll
        for (int rt = 0; rt < 4; ++rt) acc[rt][tc] = (f32x4){0.f, 0.f, 0.f, 0.f};
    for (int c = 0; c < 8; ++c) {
        bf16x8 af[4];
        #pragma unroll
        for (int rt = 0; rt < 4; ++rt)
            af[rt] = *(const bf16x8*)&B0[(rt * 16 + m) * 264 + c * 32 + qk];
        #pragma unroll
        for (int tc = 0; tc < 4; ++tc) {
            bf16x8 wfr = *(const bf16x8*)&pB2[(((w * 4 + tc) * 8 + c) * 64 + lane) * 8];
            #pragma unroll
            for (int rt = 0; rt < 4; ++rt)
                acc[rt][tc] = __builtin_amdgcn_mfma_f32_16x16x32_bf16(wfr, af[rt], acc[rt][tc], 0, 0, 0);
        }
    }
    __syncthreads();                                       // (3) h1 reads done
    {
        float qp[4] = {0.f, 0.f, 0.f, 0.f};
        #pragma unroll
        for (int tc = 0; tc < 4; ++tc) {
            const float4 bv = *(const float4*)&bias2[(w * 4 + tc) * 16 + q * 4];
            const float4 wv = *(const float4*)&w3s[(w * 4 + tc) * 16 + q * 4];
            const float bva[4] = {bv.x, bv.y, bv.z, bv.w};
            const float wva[4] = {wv.x, wv.y, wv.z, wv.w};
            #pragma unroll
            for (int rt = 0; rt < 4; ++rt) {
                ushort4 pk; float dz[4];
                #pragma unroll
                for (int i = 0; i < 4; ++i) {
                    float z = acc[rt][tc][i] + bva[i];
                    if (z > 0.f) { qp[rt] += z * wva[i]; dz[i] = wva[i]; }
                    else         { dz[i] = 0.f; }
                }
                pk.x = f2bf(dz[0]); pk.y = f2bf(dz[1]);
                pk.z = f2bf(dz[2]); pk.w = f2bf(dz[3]);
                *(ushort4*)&B0[(rt * 16 + m) * 264 + (w * 4 + tc) * 16 + q * 4] = pk;
            }
        }
        #pragma unroll
        for (int rt = 0; rt < 4; ++rt) {
            float v = qp[rt];
            v += __shfl_xor(v, 16); v += __shfl_xor(v, 32);
            if (q == 0) qpart[w][rt * 16 + m] = v;
        }
    }
    __syncthreads();                                       // (4) dz2 visible

    if (tid < RB)
        qout[row0 + tid] = qpart[0][tid] + qpart[1][tid] + qpart[2][tid] +
                           qpart[3][tid] + b3[0];

    // ---- Phase D: dh1 = dz2 @ w2^T ; dz1 = dh1 * mask -> B0
    #pragma unroll
    for (int tc = 0; tc < 4; ++tc)
        #pragma unroll
        for (int rt = 0; rt < 4; ++rt) acc[rt][tc] = (f32x4){0.f, 0.f, 0.f, 0.f};
    for (int c = 0; c < 8; ++c) {
        bf16x8 af[4];
        #pragma unroll
        for (int rt = 0; rt < 4; ++rt)
            af[rt] = *(const bf16x8*)&B0[(rt * 16 + m) * 264 + c * 32 + qk];
        #pragma unroll
        for (int tc = 0; tc < 4; ++tc) {
            bf16x8 wfr = *(const bf16x8*)&pB3[(((w * 4 + tc) * 8 + c) * 64 + lane) * 8];
            #pragma unroll
            for (int rt = 0; rt < 4; ++rt)
                acc[rt][tc] = __builtin_amdgcn_mfma_f32_16x16x32_bf16(wfr, af[rt], acc[rt][tc], 0, 0, 0);
        }
    }
    __syncthreads();                                       // (5) dz2 reads done
    #pragma unroll
    for (int rt = 0; rt < 4; ++rt)
        #pragma unroll
        for (int tc = 0; tc < 4; ++tc) {
            ushort4 pk;
            pk.x = f2bf((relumask >> (rt * 16 + tc * 4 + 0)) & 1ULL ? acc[rt][tc][0] : 0.f);
            pk.y = f2bf((relumask >> (rt * 16 + tc * 4 + 1)) & 1ULL ? acc[rt][tc][1] : 0.f);
            pk.z = f2bf((relumask >> (rt * 16 + tc * 4 + 2)) & 1ULL ? acc[rt][tc][2] : 0.f);
            pk.w = f2bf((relumask >> (rt * 16 + tc * 4 + 3)) & 1ULL ? acc[rt][tc][3] : 0.f);
            *(ushort4*)&B0[(rt * 16 + m) * 264 + (w * 4 + tc) * 16 + q * 4] = pk;
        }
    __syncthreads();                                       // (6)

    // ---- Phase E: score = dz1 @ w1[64:80]^T -> SS (LDS, no HBM round trip)
    {
        f32x4 acc2 = (f32x4){0.f, 0.f, 0.f, 0.f};
        for (int c = 0; c < 8; ++c) {
            bf16x8 af = *(const bf16x8*)&B0[(w * 16 + m) * 264 + c * 32 + qk];
            bf16x8 wfr = *(const bf16x8*)&pB4[(c * 64 + lane) * 8];
            acc2 = __builtin_amdgcn_mfma_f32_16x16x32_bf16(wfr, af, acc2, 0, 0, 0);
        }
        // lane (q,m), wave w: score row w*16+m, cols q*4..q*4+3 (stride-17 rows
        // are not 16B-aligned -> scalar stores; 2-way bank alias only)
        #pragma unroll
        for (int i = 0; i < 4; ++i)
            SS[(w * 16 + m) * 17 + q * 4 + i] = acc2[i];
    }
    __syncthreads();                 // (7) SS visible, B0 dz1 reads done

    // ================= SVGD tail (2 states, round-5-proven) ===============
    const int st = tid >> 7;          // state 0/1
    const int t  = tid & 127;         // thread within state
    const int lw = (tid >> 6) & 1;    // wave within state
    float* D2s = D2a + st * 1056;
    float* KMs = KMa + st * 1056;
    float* PPs = PPa + st * 1056;
    int*   hs  = hista + st * 256;
    const int rbase = st * 32;

    unsigned v[8];                    // this thread's 8 dist^2 values (bits)
    #pragma unroll
    for (int u = 0; u < 8; ++u) {
        int idx = t + 128 * u, i = idx >> 5, j = idx & 31;
        float s = 0.f;
        #pragma unroll
        for (int d = 0; d < 16; ++d) {
            float df = XA[(rbase + i) * 17 + d] - XA[(rbase + j) * 17 + d];
            s += df * df;
        }
        D2s[i * 33 + j] = s;
        v[u] = __float_as_uint(s);
    }

    // radix select rank-511 (bit-exact jnp.median)
    unsigned prefix = 0;
    int rank = 511;
    for (int shift = 24; shift >= 0; shift -= 8) {
        hs[t] = 0; hs[t + 128] = 0;
        __syncthreads();
        unsigned him = (shift == 24) ? 0u : (0xFFFFFFFFu << (shift + 8));
        #pragma unroll
        for (int u = 0; u < 8; ++u)
            if ((v[u] & him) == prefix)
                atomicAdd(&hs[(v[u] >> shift) & 255], 1);
        __syncthreads();
        int c0 = hs[2 * t], c1 = hs[2 * t + 1], ps = c0 + c1, inc = ps;
        #pragma unroll
        for (int off = 1; off < 64; off <<= 1) {
            int x = __shfl_up(inc, off, 64);
            if (lane >= off) inc += x;
        }
        if (lane == 63) wsumS[st][lw] = inc;
        __syncthreads();
        int incl = inc + ((lw == 1) ? wsumS[st][0] : 0);
        int ex0 = incl - ps, ex1 = incl - c1;
        if (c0 > 0 && rank >= ex0 && rank < ex0 + c0) { bbin[st] = 2 * t;     bexcl[st] = ex0; }
        if (c1 > 0 && rank >= ex1 && rank < ex1 + c1) { bbin[st] = 2 * t + 1; bexcl[st] = ex1; }
        __syncthreads();
        prefix |= ((unsigned)bbin[st]) << shift;
        rank -= bexcl[st];
    }
    const float v1 = __uint_as_float(prefix);

    // rank-512: v1 if count(<=v1)>=513 else min(x>v1)
    {
        int cle = 0; unsigned mgt = 0xFFFFFFFFu;
        #pragma unroll
        for (int u = 0; u < 8; ++u) {
            if (v[u] <= prefix) cle++;
            else mgt = min(mgt, v[u]);
        }
        #pragma unroll
        for (int off = 1; off < 64; off <<= 1) {
            cle += __shfl_xor(cle, off);
            mgt = min(mgt, (unsigned)__shfl_xor((int)mgt, off));
        }
        if (lane == 0) { redc[st][lw] = cle; redm[st][lw] = mgt; }
        __syncthreads();
        if (t == 0) {
            int C = redc[st][0] + redc[st][1];
            unsigned M = min(redm[st][0], redm[st][1]);
            float v2 = (C >= 513) ? v1 : __uint_as_float(M);
            medsh[st] = 0.5f * (v1 + v2);
        }
        __syncthreads();
    }
    const float gamma = 1.0f / (2.0f * (medsh[st] / LN32 + 1e-8f));

    // K and P
    #pragma unroll
    for (int u = 0; u < 8; ++u) {
        int idx = t + 128 * u, i = idx >> 5, j = idx & 31;
        KMs[i * 33 + j] = __expf(-gamma * __uint_as_float(v[u]));
        float p = 0.f;
        #pragma unroll
        for (int d = 0; d < 16; ++d)
            p += (XA[(rbase + i) * 17 + d] - XA[(rbase + j) * 17 + d]) *
                 SS[(rbase + j) * 17 + d];
        PPs[i * 33 + j] = p;
    }
    __syncthreads();

    // phi + particle update -> global a_next
    #pragma unroll
    for (int u = 0; u < 4; ++u) {
        int idx = t + 128 * u, i = idx >> 4, d = idx & 15;
        float xi = XA[(rbase + i) * 17 + d];
        float s1 = 0.f, s2 = 0.f;
        #pragma unroll
        for (int j = 0; j < 32; ++j) {
            float kk = KMs[i * 33 + j];
            s1 += kk * SS[(rbase + j) * 17 + d];
            s2 += (xi - XA[(rbase + j) * 17 + d]) * kk;
        }
        float phi = (s1 + 2.f * gamma * s2) * (1.f / 32.f);
        float av = xi + 0.1f * phi;
        av = fminf(fmaxf(av, -1.f), 1.f);
        a_next[(size_t)(row0 + rbase + i) * 16 + d] = av;
    }

    // logp correction (4 threads per particle)
    {
        int i = t >> 2, jj = t & 3;
        float a1 = 0.f, a2s = 0.f;
        #pragma unroll
        for (int u = 0; u < 8; ++u) {
            int j = jj + 4 * u;
            float kk = KMs[i * 33 + j];
            a1  += kk * PPs[i * 33 + j];
            a2s += (2.f * gamma * D2s[i * 33 + j] - 16.f) * kk;
        }
        a1  += __shfl_xor(a1, 1);  a1  += __shfl_xor(a1, 2);
        a2s += __shfl_xor(a2s, 1); a2s += __shfl_xor(a2s, 2);
        if (jj == 0) {
            float tmp1 = -2.f * gamma * a1  * (1.f / 32.f);
            float tmp2 = -2.f * gamma * a2s * (1.f / 32.f);
            float prev = first ? 0.f : logp_in[row0 + rbase + i];
            logp_out[row0 + rbase + i] = prev - 0.1f * (tmp1 + tmp2);
        }
    }
}

// ---------------------------------------------------------------------------
extern "C" void kernel_launch(void* const* d_in, const int* in_sizes, int n_in,
                              void* d_out, int out_size, void* d_ws, size_t ws_size,
                              hipStream_t stream) {
    const float* obs = (const float*)d_in[0];
    const float* a0  = (const float*)d_in[1];
    const float* w1  = (const float*)d_in[2];
    const float* b1  = (const float*)d_in[3];
    const float* w2  = (const float*)d_in[4];
    const float* b2  = (const float*)d_in[5];
    const float* w3  = (const float*)d_in[6];
    const float* b3  = (const float*)d_in[7];

    float* out_a    = (float*)d_out;                 // [BN,16]
    float* out_logp = out_a + (size_t)BNROWS * 16;   // [BN]
    float* out_q    = out_logp + BNROWS;             // [BN]

    char* p = (char*)d_ws;
    ushort* pB1 = (ushort*)p; p += 24576 * 2;
    ushort* pB2 = (ushort*)p; p += 65536 * 2;
    ushort* pB3 = (ushort*)p; p += 65536 * 2;
    ushort* pB4 = (ushort*)p; p += 4096 * 2;
    ushort* obs_bf = (ushort*)p; p += (size_t)BNROWS * 64 * 2;
    float* abuf0 = (float*)p; p += (size_t)BNROWS * 16 * 4;
    float* abuf1 = (float*)p; p += (size_t)BNROWS * 16 * 4;
    float* logp  = (float*)p; p += (size_t)BNROWS * 4;
    float* qtmp  = (float*)p;

    prep_pack<<<78, 256, 0, stream>>>(w1, w2, pB1, pB2, pB3, pB4);
    obs_to_bf16<<<8192, 256, 0, stream>>>(obs, obs_bf);

    const int MB = BNROWS / RB;   // 2048 blocks

    // step 1
    mlp_svgd<<<MB, 256, 0, stream>>>(obs_bf, a0, b1, b2, w3, b3,
                                     pB1, pB2, pB3, pB4,
                                     nullptr, logp, abuf0, qtmp, 1);
    // step 2
    mlp_svgd<<<MB, 256, 0, stream>>>(obs_bf, abuf0, b1, b2, w3, b3,
                                     pB1, pB2, pB3, pB4,
                                     logp, logp, abuf1, qtmp, 0);
    // step 3 (q of this step is the q_vals output)
    mlp_svgd<<<MB, 256, 0, stream>>>(obs_bf, abuf1, b1, b2, w3, b3,
                                     pB1, pB2, pB3, pB4,
                                     logp, out_logp, out_a, out_q, 0);
}

// Round 8
// 483.228 us; speedup vs baseline: 1.1836x; 1.1836x over previous
//
#include <hip/hip_runtime.h>
#include <hip/hip_bf16.h>
#include <math.h>

#define BNROWS (4096*32)   // 131072
#define RB     64          // rows per MLP block
#define LN32   3.4657359027997265f

typedef __attribute__((ext_vector_type(8))) short bf16x8;
typedef __attribute__((ext_vector_type(4))) float f32x4;

static __device__ __forceinline__ ushort f2bf(float x) {
    union { __hip_bfloat16 h; ushort u; } cv;
    cv.h = __float2bfloat16(x);
    return cv.u;
}

// ---------------------------------------------------------------------------
__global__ void obs_to_bf16(const float* __restrict__ obs,
                            ushort* __restrict__ obs_bf) {
    size_t i = ((size_t)blockIdx.x * 256 + threadIdx.x) * 4;
    float4 v = *(const float4*)&obs[i];
    ushort4 o;
    o.x = f2bf(v.x); o.y = f2bf(v.y); o.z = f2bf(v.z); o.w = f2bf(v.w);
    *(ushort4*)&obs_bf[i] = o;
}

// ---------------------------------------------------------------------------
// Pack weights into MFMA fragment order (lane-contiguous 16B loads).
// Lane (q,m): element j -> W[k = c*32 + q*8 + j][n = tile*16 + m].
__global__ void prep_pack(const float* __restrict__ w1,
                          const float* __restrict__ w2,
                          ushort* __restrict__ pB1, ushort* __restrict__ pB2,
                          ushort* __restrict__ pB3, ushort* __restrict__ pB4) {
    int g = blockIdx.x * 256 + threadIdx.x;   // 19968 total
    ushort out[8];
    ushort* dst;
    if (g < 3072) {
        int lane = g & 63, gc = g >> 6;
        int t = gc / 3, c = gc % 3;
        int m = lane & 15, q = lane >> 4, n = t * 16 + m;
        #pragma unroll
        for (int j = 0; j < 8; ++j) {
            int k = c * 32 + q * 8 + j;
            out[j] = f2bf((k < 80) ? w1[k * 256 + n] : 0.f);
        }
        dst = &pB1[g * 8];
    } else if (g < 11264) {
        int gg = g - 3072;
        int lane = gg & 63, gc = gg >> 6;
        int t = gc >> 3, c = gc & 7;
        int m = lane & 15, q = lane >> 4, n = t * 16 + m;
        #pragma unroll
        for (int j = 0; j < 8; ++j)
            out[j] = f2bf(w2[(c * 32 + q * 8 + j) * 256 + n]);
        dst = &pB2[gg * 8];
    } else if (g < 19456) {
        int gg = g - 11264;
        int lane = gg & 63, gc = gg >> 6;
        int t = gc >> 3, c = gc & 7;
        int m = lane & 15, q = lane >> 4;
        #pragma unroll
        for (int j = 0; j < 8; ++j)
            out[j] = f2bf(w2[(t * 16 + m) * 256 + c * 32 + q * 8 + j]);
        dst = &pB3[gg * 8];
    } else if (g < 19968) {
        int gg = g - 19456;
        int lane = gg & 63, c = gg >> 6;
        int m = lane & 15, q = lane >> 4;
        #pragma unroll
        for (int j = 0; j < 8; ++j)
            out[j] = f2bf(w1[(64 + m) * 256 + c * 32 + q * 8 + j]);
        dst = &pB4[gg * 8];
    } else return;
    *(uint4*)dst = *(uint4*)out;
}

// ---------------------------------------------------------------------------
// Fused critic forward + VJP wrt actions, bf16 MFMA with swapped operands
// (round-6 structure, UNCHANGED — 70 us/dispatch, no spill).
// Plain __launch_bounds__(256): min-wave bounds caused scratch spill (r3/r4/r5).
__global__ __launch_bounds__(256) void mlp_mfma(
    const ushort* __restrict__ obs_bf,  // [BN,64] bf16
    const float* __restrict__ a_in,     // [BN,16]
    const float* __restrict__ b1,       // [256]
    const float* __restrict__ b2,       // [256]
    const float* __restrict__ w3,       // [256]
    const float* __restrict__ b3,       // [1]
    const ushort* __restrict__ pB1, const ushort* __restrict__ pB2,
    const ushort* __restrict__ pB3, const ushort* __restrict__ pB4,
    float* __restrict__ score,          // [BN,16]
    float* __restrict__ qout)           // [BN]
{
    __shared__ __align__(16) ushort B0[RB * 264];   // h1 -> dz2 -> dz1
    __shared__ __align__(16) ushort B1s[RB * 104];  // h0
    __shared__ float qpart[4][RB];
    __shared__ float bias1[256], bias2[256], w3s[256];

    const int tid  = threadIdx.x;
    const int row0 = blockIdx.x * RB;

    // ---- Phase A: stage h0 = [obs_bf16 | a->bf16 | 0pad] at stride 104
    for (int u = tid; u < 512; u += 256) {
        int r = u >> 3, ch = u & 7;
        *(uint4*)&B1s[r * 104 + ch * 8] =
            *(const uint4*)&obs_bf[(size_t)(row0 + r) * 64 + ch * 8];
    }
    {
        int r = tid >> 2, d0 = (tid & 3) * 4;
        float4 av = *(const float4*)&a_in[(size_t)(row0 + r) * 16 + d0];
        ushort4 pv;
        pv.x = f2bf(av.x); pv.y = f2bf(av.y); pv.z = f2bf(av.z); pv.w = f2bf(av.w);
        *(ushort4*)&B1s[r * 104 + 64 + d0] = pv;
        ushort4 zv; zv.x = zv.y = zv.z = zv.w = 0;
        *(ushort4*)&B1s[r * 104 + 80 + d0] = zv;
    }
    bias1[tid] = b1[tid]; bias2[tid] = b2[tid]; w3s[tid] = w3[tid];
    __syncthreads();                                       // (1)

    const int lane = tid & 63;
    const int w    = tid >> 6;
    const int m    = lane & 15;
    const int q    = lane >> 4;
    const int qk   = q * 8;

    f32x4 acc[4][4];
    unsigned long long relumask = 0ULL;

    // ---- Phase B: z1 = h0 @ w1 (+b1) ; relu -> B0 ; mask -> regs
    #pragma unroll
    for (int tc = 0; tc < 4; ++tc)
        #pragma unroll
        for (int rt = 0; rt < 4; ++rt) acc[rt][tc] = (f32x4){0.f, 0.f, 0.f, 0.f};
    for (int c = 0; c < 3; ++c) {
        bf16x8 af[4];
        #pragma unroll
        for (int rt = 0; rt < 4; ++rt)
            af[rt] = *(const bf16x8*)&B1s[(rt * 16 + m) * 104 + c * 32 + qk];
        #pragma unroll
        for (int tc = 0; tc < 4; ++tc) {
            bf16x8 wfr = *(const bf16x8*)&pB1[(((w * 4 + tc) * 3 + c) * 64 + lane) * 8];
            #pragma unroll
            for (int rt = 0; rt < 4; ++rt)
                acc[rt][tc] = __builtin_amdgcn_mfma_f32_16x16x32_bf16(wfr, af[rt], acc[rt][tc], 0, 0, 0);
        }
    }
    #pragma unroll
    for (int tc = 0; tc < 4; ++tc) {
        const float4 bv = *(const float4*)&bias1[(w * 4 + tc) * 16 + q * 4];
        const float bva[4] = {bv.x, bv.y, bv.z, bv.w};
        #pragma unroll
        for (int rt = 0; rt < 4; ++rt) {
            ushort4 pk;
            float z0 = acc[rt][tc][0] + bva[0];
            float z1 = acc[rt][tc][1] + bva[1];
            float z2 = acc[rt][tc][2] + bva[2];
            float z3 = acc[rt][tc][3] + bva[3];
            if (z0 > 0.f) relumask |= 1ULL << (rt * 16 + tc * 4 + 0);
            if (z1 > 0.f) relumask |= 1ULL << (rt * 16 + tc * 4 + 1);
            if (z2 > 0.f) relumask |= 1ULL << (rt * 16 + tc * 4 + 2);
            if (z3 > 0.f) relumask |= 1ULL << (rt * 16 + tc * 4 + 3);
            pk.x = f2bf(fmaxf(z0, 0.f)); pk.y = f2bf(fmaxf(z1, 0.f));
            pk.z = f2bf(fmaxf(z2, 0.f)); pk.w = f2bf(fmaxf(z3, 0.f));
            *(ushort4*)&B0[(rt * 16 + m) * 264 + (w * 4 + tc) * 16 + q * 4] = pk;
        }
    }
    __syncthreads();                                       // (2)

    // ---- Phase C: z2 = h1 @ w2 (+b2) ; q partials ; dz2 -> B0
    #pragma unroll
    for (int tc = 0; tc < 4; ++tc)
        #pragma unroll
        for (int rt = 0; rt < 4; ++rt) acc[rt][tc] = (f32x4){0.f, 0.f, 0.f, 0.f};
    for (int c = 0; c < 8; ++c) {
        bf16x8 af[4];
        #pragma unroll
        for (int rt = 0; rt < 4; ++rt)
            af[rt] = *(const bf16x8*)&B0[(rt * 16 + m) * 264 + c * 32 + qk];
        #pragma unroll
        for (int tc = 0; tc < 4; ++tc) {
            bf16x8 wfr = *(const bf16x8*)&pB2[(((w * 4 + tc) * 8 + c) * 64 + lane) * 8];
            #pragma unroll
            for (int rt = 0; rt < 4; ++rt)
                acc[rt][tc] = __builtin_amdgcn_mfma_f32_16x16x32_bf16(wfr, af[rt], acc[rt][tc], 0, 0, 0);
        }
    }
    __syncthreads();                                       // (3)
    {
        float qp[4] = {0.f, 0.f, 0.f, 0.f};
        #pragma unroll
        for (int tc = 0; tc < 4; ++tc) {
            const float4 bv = *(const float4*)&bias2[(w * 4 + tc) * 16 + q * 4];
            const float4 wv = *(const float4*)&w3s[(w * 4 + tc) * 16 + q * 4];
            const float bva[4] = {bv.x, bv.y, bv.z, bv.w};
            const float wva[4] = {wv.x, wv.y, wv.z, wv.w};
            #pragma unroll
            for (int rt = 0; rt < 4; ++rt) {
                ushort4 pk; float dz[4];
                #pragma unroll
                for (int i = 0; i < 4; ++i) {
                    float z = acc[rt][tc][i] + bva[i];
                    if (z > 0.f) { qp[rt] += z * wva[i]; dz[i] = wva[i]; }
                    else         { dz[i] = 0.f; }
                }
                pk.x = f2bf(dz[0]); pk.y = f2bf(dz[1]);
                pk.z = f2bf(dz[2]); pk.w = f2bf(dz[3]);
                *(ushort4*)&B0[(rt * 16 + m) * 264 + (w * 4 + tc) * 16 + q * 4] = pk;
            }
        }
        #pragma unroll
        for (int rt = 0; rt < 4; ++rt) {
            float v = qp[rt];
            v += __shfl_xor(v, 16); v += __shfl_xor(v, 32);
            if (q == 0) qpart[w][rt * 16 + m] = v;
        }
    }
    __syncthreads();                                       // (4)

    if (tid < RB)
        qout[row0 + tid] = qpart[0][tid] + qpart[1][tid] + qpart[2][tid] +
                           qpart[3][tid] + b3[0];

    // ---- Phase D: dh1 = dz2 @ w2^T ; dz1 = dh1 * mask -> B0
    #pragma unroll
    for (int tc = 0; tc < 4; ++tc)
        #pragma unroll
        for (int rt = 0; rt < 4; ++rt) acc[rt][tc] = (f32x4){0.f, 0.f, 0.f, 0.f};
    for (int c = 0; c < 8; ++c) {
        bf16x8 af[4];
        #pragma unroll
        for (int rt = 0; rt < 4; ++rt)
            af[rt] = *(const bf16x8*)&B0[(rt * 16 + m) * 264 + c * 32 + qk];
        #pragma unroll
        for (int tc = 0; tc < 4; ++tc) {
            bf16x8 wfr = *(const bf16x8*)&pB3[(((w * 4 + tc) * 8 + c) * 64 + lane) * 8];
            #pragma unroll
            for (int rt = 0; rt < 4; ++rt)
                acc[rt][tc] = __builtin_amdgcn_mfma_f32_16x16x32_bf16(wfr, af[rt], acc[rt][tc], 0, 0, 0);
        }
    }
    __syncthreads();                                       // (5)
    #pragma unroll
    for (int rt = 0; rt < 4; ++rt)
        #pragma unroll
        for (int tc = 0; tc < 4; ++tc) {
            ushort4 pk;
            pk.x = f2bf((relumask >> (rt * 16 + tc * 4 + 0)) & 1ULL ? acc[rt][tc][0] : 0.f);
            pk.y = f2bf((relumask >> (rt * 16 + tc * 4 + 1)) & 1ULL ? acc[rt][tc][1] : 0.f);
            pk.z = f2bf((relumask >> (rt * 16 + tc * 4 + 2)) & 1ULL ? acc[rt][tc][2] : 0.f);
            pk.w = f2bf((relumask >> (rt * 16 + tc * 4 + 3)) & 1ULL ? acc[rt][tc][3] : 0.f);
            *(ushort4*)&B0[(rt * 16 + m) * 264 + (w * 4 + tc) * 16 + q * 4] = pk;
        }
    __syncthreads();                                       // (6)

    // ---- Phase E: score = dz1 @ w1[64:80]^T
    {
        f32x4 acc2 = (f32x4){0.f, 0.f, 0.f, 0.f};
        for (int c = 0; c < 8; ++c) {
            bf16x8 af = *(const bf16x8*)&B0[(w * 16 + m) * 264 + c * 32 + qk];
            bf16x8 wfr = *(const bf16x8*)&pB4[(c * 64 + lane) * 8];
            acc2 = __builtin_amdgcn_mfma_f32_16x16x32_bf16(wfr, af, acc2, 0, 0, 0);
        }
        float4 o; o.x = acc2[0]; o.y = acc2[1]; o.z = acc2[2]; o.w = acc2[3];
        *(float4*)&score[(size_t)(row0 + w * 16 + m) * 16 + q * 4] = o;
    }
}

// ---------------------------------------------------------------------------
// SVGD v2: ONE WAVE PER STATE (4 states / 256-thread block, 1024 blocks).
// No cross-wave LDS sharing => ZERO __syncthreads (wave-ordered LDS via
// hardware lgkmcnt). Per-lane register tiles: lane owns particle column
// j = lane&31 (xj/sj) and entries (i = 2u + lane/32, j) of the 32x32 pair
// matrix (v=dist2 bits, p=P, kreg=K). Median: wave-local 4-pass radix select
// (LDS hist overlaying K's storage, shfl scan + ballot) — bit-exact
// jnp.median. X/S stride 20 (16B-aligned rows), K stride 33.
// Plain __launch_bounds__(256): min-wave bounds spill (r3 post-mortem).
__global__ __launch_bounds__(256) void svgd_kernel(
    const float* __restrict__ a_in,    // [BN,16]
    const float* __restrict__ score,   // [BN,16]
    const float* __restrict__ logp_in, // [BN] (ignored if first)
    float* __restrict__ logp_out,      // [BN]
    float* __restrict__ a_out,         // [BN,16]
    int first)
{
    __shared__ __align__(16) float Xs[4][32 * 20];
    __shared__ __align__(16) float Ss[4][32 * 20];
    __shared__ __align__(16) float Ks[4][32 * 33];   // first 256 f double as hist

    const int tid  = threadIdx.x;
    const int wv   = tid >> 6;
    const int l    = tid & 63;
    const int sIdx = blockIdx.x * 4 + wv;
    const size_t base = (size_t)sIdx * 512;

    float* X = Xs[wv];
    float* S = Ss[wv];
    float* K = Ks[wv];
    int*  hist = (int*)K;              // used strictly BEFORE K is written

    // ---- stage a/score (this wave only; no barrier ever needed)
    #pragma unroll
    for (int u = 0; u < 2; ++u) {
        int idx = (l + 64 * u) * 4;            // 0..508 step 4
        int r = idx >> 4, d = idx & 15;
        *(float4*)&X[r * 20 + d] = *(const float4*)&a_in[base + idx];
        *(float4*)&S[r * 20 + d] = *(const float4*)&score[base + idx];
    }

    const int j = l & 31;              // this lane's column particle
    const int h = l >> 5;              // row-half selector

    float xj[16], sj[16];
    #pragma unroll
    for (int d4 = 0; d4 < 4; ++d4) {
        float4 xv = *(const float4*)&X[j * 20 + d4 * 4];
        xj[d4*4+0]=xv.x; xj[d4*4+1]=xv.y; xj[d4*4+2]=xv.z; xj[d4*4+3]=xv.w;
        float4 sv = *(const float4*)&S[j * 20 + d4 * 4];
        sj[d4*4+0]=sv.x; sj[d4*4+1]=sv.y; sj[d4*4+2]=sv.z; sj[d4*4+3]=sv.w;
    }

    // ---- dist^2 and P fused: entry (i = 2u+h, j) per u
    unsigned v[16]; float p[16];
    #pragma unroll
    for (int u = 0; u < 16; ++u) {
        int i = 2 * u + h;
        float d2 = 0.f, pp = 0.f;
        #pragma unroll
        for (int d4 = 0; d4 < 4; ++d4) {
            float4 xi = *(const float4*)&X[i * 20 + d4 * 4];
            float xia[4] = {xi.x, xi.y, xi.z, xi.w};
            #pragma unroll
            for (int dd = 0; dd < 4; ++dd) {
                float df = xia[dd] - xj[d4 * 4 + dd];
                d2 = fmaf(df, df, d2);
                pp = fmaf(df, sj[d4 * 4 + dd], pp);
            }
        }
        v[u] = __float_as_uint(d2);
        p[u] = pp;
    }

    // ---- wave-local radix select: rank 511 of the 1024 values
    unsigned prefix = 0; int rank = 511;
    #pragma unroll
    for (int pass = 0; pass < 4; ++pass) {
        const int shift = 24 - pass * 8;
        hist[l] = 0; hist[l + 64] = 0; hist[l + 128] = 0; hist[l + 192] = 0;
        const unsigned him = (pass == 0) ? 0u : (0xFFFFFFFFu << (shift + 8));
        #pragma unroll
        for (int u = 0; u < 16; ++u)
            if ((v[u] & him) == prefix)
                atomicAdd(&hist[(v[u] >> shift) & 255], 1);
        int c0 = hist[4 * l + 0], c1 = hist[4 * l + 1];
        int c2 = hist[4 * l + 2], c3 = hist[4 * l + 3];
        int cs = c0 + c1 + c2 + c3;
        int inc = cs;
        #pragma unroll
        for (int off = 1; off < 64; off <<= 1) {
            int t = __shfl_up(inc, off, 64);
            if (l >= off) inc += t;
        }
        int run = inc - cs;            // exclusive prefix of this lane's bins
        int bin = -1, bex = 0;
        if (rank >= run && rank < run + c0) { bin = 4 * l + 0; bex = run; }
        run += c0;
        if (bin < 0 && rank >= run && rank < run + c1) { bin = 4 * l + 1; bex = run; }
        run += c1;
        if (bin < 0 && rank >= run && rank < run + c2) { bin = 4 * l + 2; bex = run; }
        run += c2;
        if (bin < 0 && rank >= run && rank < run + c3) { bin = 4 * l + 3; bex = run; }
        unsigned long long ball = __ballot(bin >= 0);
        int src = __ffsll((unsigned long long)ball) - 1;
        bin = __shfl(bin, src, 64);
        bex = __shfl(bex, src, 64);
        prefix |= ((unsigned)bin) << shift;
        rank -= bex;
    }
    const float v1 = __uint_as_float(prefix);

    // rank-512: v1 if count(<=v1)>=513 else min(x>v1)  (butterfly -> all lanes)
    int cle = 0; unsigned mgt = 0xFFFFFFFFu;
    #pragma unroll
    for (int u = 0; u < 16; ++u) {
        if (v[u] <= prefix) cle++;
        else mgt = min(mgt, v[u]);
    }
    #pragma unroll
    for (int off = 1; off < 64; off <<= 1) {
        cle += __shfl_xor(cle, off);
        mgt = min(mgt, (unsigned)__shfl_xor((int)mgt, off));
    }
    const float v2  = (cle >= 513) ? v1 : __uint_as_float(mgt);
    const float med = 0.5f * (v1 + v2);
    const float gamma = 1.0f / (2.0f * (med / LN32 + 1e-8f));

    // ---- K = exp(-gamma d2): regs + LDS (row i stride 33, conflict-free)
    float kreg[16];
    #pragma unroll
    for (int u = 0; u < 16; ++u) {
        float kk = __expf(-gamma * __uint_as_float(v[u]));
        kreg[u] = kk;
        K[(2 * u + h) * 33 + j] = kk;
    }

    // ---- phi + particle update: 8 outputs (i = o>>4, d = o&15) per lane
    #pragma unroll
    for (int u = 0; u < 8; ++u) {
        int o = 64 * u + l, i = o >> 4, d = o & 15;
        float xi = X[i * 20 + d];
        float s1 = 0.f, s2 = 0.f;
        #pragma unroll 8
        for (int jj = 0; jj < 32; ++jj) {
            float kk = K[i * 33 + jj];
            s1 = fmaf(kk, S[jj * 20 + d], s1);
            s2 = fmaf(kk, xi - X[jj * 20 + d], s2);
        }
        float phi = (s1 + 2.f * gamma * s2) * (1.f / 32.f);
        float av = fminf(fmaxf(xi + 0.1f * phi, -1.f), 1.f);
        a_out[base + o] = av;                   // o == i*16+d, coalesced
    }

    // ---- logp: reduce K*P and (2g*d2-16)*K over j (32-lane butterfly)
    #pragma unroll
    for (int u = 0; u < 16; ++u) {
        float val1 = kreg[u] * p[u];
        float val2 = (2.f * gamma * __uint_as_float(v[u]) - 16.f) * kreg[u];
        #pragma unroll
        for (int off = 1; off < 32; off <<= 1) {
            val1 += __shfl_xor(val1, off);
            val2 += __shfl_xor(val2, off);
        }
        if (j == u) {
            int i = 2 * u + h;
            float tmp = -2.f * gamma * (val1 + val2) * (1.f / 32.f);
            float prev = first ? 0.f : logp_in[sIdx * 32 + i];
            logp_out[sIdx * 32 + i] = prev - 0.1f * tmp;
        }
    }
}

// ---------------------------------------------------------------------------
extern "C" void kernel_launch(void* const* d_in, const int* in_sizes, int n_in,
                              void* d_out, int out_size, void* d_ws, size_t ws_size,
                              hipStream_t stream) {
    const float* obs = (const float*)d_in[0];
    const float* a0  = (const float*)d_in[1];
    const float* w1  = (const float*)d_in[2];
    const float* b1  = (const float*)d_in[3];
    const float* w2  = (const float*)d_in[4];
    const float* b2  = (const float*)d_in[5];
    const float* w3  = (const float*)d_in[6];
    const float* b3  = (const float*)d_in[7];

    float* out_a    = (float*)d_out;                 // [BN,16]
    float* out_logp = out_a + (size_t)BNROWS * 16;   // [BN]
    float* out_q    = out_logp + BNROWS;             // [BN]

    char* p = (char*)d_ws;
    ushort* pB1 = (ushort*)p; p += 24576 * 2;
    ushort* pB2 = (ushort*)p; p += 65536 * 2;
    ushort* pB3 = (ushort*)p; p += 65536 * 2;
    ushort* pB4 = (ushort*)p; p += 4096 * 2;
    ushort* obs_bf = (ushort*)p; p += (size_t)BNROWS * 64 * 2;
    float* abuf0 = (float*)p; p += (size_t)BNROWS * 16 * 4;
    float* abuf1 = (float*)p; p += (size_t)BNROWS * 16 * 4;
    float* scr   = (float*)p; p += (size_t)BNROWS * 16 * 4;
    float* logp  = (float*)p; p += (size_t)BNROWS * 4;
    float* qtmp  = (float*)p;

    prep_pack<<<78, 256, 0, stream>>>(w1, w2, pB1, pB2, pB3, pB4);
    obs_to_bf16<<<8192, 256, 0, stream>>>(obs, obs_bf);

    const int MB = BNROWS / RB;   // 2048 blocks
    const int SB = 4096 / 4;      // 1024 blocks, 4 states each

    // step 1
    mlp_mfma<<<MB, 256, 0, stream>>>(obs_bf, a0, b1, b2, w3, b3,
                                     pB1, pB2, pB3, pB4, scr, qtmp);
    svgd_kernel<<<SB, 256, 0, stream>>>(a0, scr, nullptr, logp, abuf0, 1);
    // step 2
    mlp_mfma<<<MB, 256, 0, stream>>>(obs_bf, abuf0, b1, b2, w3, b3,
                                     pB1, pB2, pB3, pB4, scr, qtmp);
    svgd_kernel<<<SB, 256, 0, stream>>>(abuf0, scr, logp, logp, abuf1, 0);
    // step 3 (q of this step is the q_vals output)
    mlp_mfma<<<MB, 256, 0, stream>>>(obs_bf, abuf1, b1, b2, w3, b3,
                                     pB1, pB2, pB3, pB4, scr, out_q);
    svgd_kernel<<<SB, 256, 0, stream>>>(abuf1, scr, logp, out_logp, out_a, 0);
}

// Round 9
// 428.229 us; speedup vs baseline: 1.3356x; 1.1284x over previous
//
#include <hip/hip_runtime.h>
#include <hip/hip_bf16.h>
#include <math.h>

#define BNROWS (4096*32)   // 131072
#define RB     64          // rows per MLP block
#define LN32   3.4657359027997265f

typedef __attribute__((ext_vector_type(8))) short bf16x8;
typedef __attribute__((ext_vector_type(4))) float f32x4;

static __device__ __forceinline__ ushort f2bf(float x) {
    union { __hip_bfloat16 h; ushort u; } cv;
    cv.h = __float2bfloat16(x);
    return cv.u;
}

// ---------------------------------------------------------------------------
__global__ void obs_to_bf16(const float* __restrict__ obs,
                            ushort* __restrict__ obs_bf) {
    size_t i = ((size_t)blockIdx.x * 256 + threadIdx.x) * 4;
    float4 v = *(const float4*)&obs[i];
    ushort4 o;
    o.x = f2bf(v.x); o.y = f2bf(v.y); o.z = f2bf(v.z); o.w = f2bf(v.w);
    *(ushort4*)&obs_bf[i] = o;
}

// ---------------------------------------------------------------------------
// Pack weights into MFMA fragment order (lane-contiguous 16B loads).
// Lane (q,m): element j -> W[k = c*32 + q*8 + j][n = tile*16 + m].
__global__ void prep_pack(const float* __restrict__ w1,
                          const float* __restrict__ w2,
                          ushort* __restrict__ pB1, ushort* __restrict__ pB2,
                          ushort* __restrict__ pB3, ushort* __restrict__ pB4) {
    int g = blockIdx.x * 256 + threadIdx.x;   // 19968 total
    ushort out[8];
    ushort* dst;
    if (g < 3072) {
        int lane = g & 63, gc = g >> 6;
        int t = gc / 3, c = gc % 3;
        int m = lane & 15, q = lane >> 4, n = t * 16 + m;
        #pragma unroll
        for (int j = 0; j < 8; ++j) {
            int k = c * 32 + q * 8 + j;
            out[j] = f2bf((k < 80) ? w1[k * 256 + n] : 0.f);
        }
        dst = &pB1[g * 8];
    } else if (g < 11264) {
        int gg = g - 3072;
        int lane = gg & 63, gc = gg >> 6;
        int t = gc >> 3, c = gc & 7;
        int m = lane & 15, q = lane >> 4, n = t * 16 + m;
        #pragma unroll
        for (int j = 0; j < 8; ++j)
            out[j] = f2bf(w2[(c * 32 + q * 8 + j) * 256 + n]);
        dst = &pB2[gg * 8];
    } else if (g < 19456) {
        int gg = g - 11264;
        int lane = gg & 63, gc = gg >> 6;
        int t = gc >> 3, c = gc & 7;
        int m = lane & 15, q = lane >> 4;
        #pragma unroll
        for (int j = 0; j < 8; ++j)
            out[j] = f2bf(w2[(t * 16 + m) * 256 + c * 32 + q * 8 + j]);
        dst = &pB3[gg * 8];
    } else if (g < 19968) {
        int gg = g - 19456;
        int lane = gg & 63, c = gg >> 6;
        int m = lane & 15, q = lane >> 4;
        #pragma unroll
        for (int j = 0; j < 8; ++j)
            out[j] = f2bf(w1[(64 + m) * 256 + c * 32 + q * 8 + j]);
        dst = &pB4[gg * 8];
    } else return;
    *(uint4*)dst = *(uint4*)out;
}

// ---------------------------------------------------------------------------
// Fused critic forward + VJP, bf16 MFMA, swapped operands (round-6 layout).
// Round-9 change: 512 threads / 8 waves, wave w owns col-tiles {2w, 2w+1} x
// all 4 row-tiles (acc 64->32 VGPRs, per-wave serial MFMA halved, 2x TLP).
// Plain __launch_bounds__(512): min-wave bounds caused scratch spill (r3/r4/r5).
__global__ __launch_bounds__(512) void mlp_mfma(
    const ushort* __restrict__ obs_bf,  // [BN,64] bf16
    const float* __restrict__ a_in,     // [BN,16]
    const float* __restrict__ b1,       // [256]
    const float* __restrict__ b2,       // [256]
    const float* __restrict__ w3,       // [256]
    const float* __restrict__ b3,       // [1]
    const ushort* __restrict__ pB1, const ushort* __restrict__ pB2,
    const ushort* __restrict__ pB3, const ushort* __restrict__ pB4,
    float* __restrict__ score,          // [BN,16]
    float* __restrict__ qout)           // [BN]
{
    __shared__ __align__(16) ushort B0[RB * 264];   // h1 -> dz2 -> dz1
    __shared__ __align__(16) ushort B1s[RB * 104];  // h0
    __shared__ float qpart[8][RB];
    __shared__ float bias1[256], bias2[256], w3s[256];

    const int tid  = threadIdx.x;
    const int row0 = blockIdx.x * RB;

    // ---- Phase A: stage h0 = [obs_bf16 | a->bf16 | 0pad] at stride 104
    {
        int r = tid >> 3, ch = tid & 7;                    // 512 units exactly
        *(uint4*)&B1s[r * 104 + ch * 8] =
            *(const uint4*)&obs_bf[(size_t)(row0 + r) * 64 + ch * 8];
    }
    if (tid < 256) {
        int r = tid >> 2, d0 = (tid & 3) * 4;
        float4 av = *(const float4*)&a_in[(size_t)(row0 + r) * 16 + d0];
        ushort4 pv;
        pv.x = f2bf(av.x); pv.y = f2bf(av.y); pv.z = f2bf(av.z); pv.w = f2bf(av.w);
        *(ushort4*)&B1s[r * 104 + 64 + d0] = pv;
        ushort4 zv; zv.x = zv.y = zv.z = zv.w = 0;
        *(ushort4*)&B1s[r * 104 + 80 + d0] = zv;
        bias1[tid] = b1[tid]; bias2[tid] = b2[tid]; w3s[tid] = w3[tid];
    }
    __syncthreads();                                       // (1)

    const int lane = tid & 63;
    const int w    = tid >> 6;        // wave 0..7 -> col-tiles {2w, 2w+1}
    const int m    = lane & 15;
    const int q    = lane >> 4;
    const int qk   = q * 8;

    f32x4 acc[4][2];                  // [row-tile][col-tile-in-wave]
    unsigned relumask = 0u;           // 32 bits: rt*8 + tc*4 + i

    // ---- Phase B: z1 = h0 @ w1 (+b1) ; relu -> B0 ; mask -> regs
    #pragma unroll
    for (int tc = 0; tc < 2; ++tc)
        #pragma unroll
        for (int rt = 0; rt < 4; ++rt) acc[rt][tc] = (f32x4){0.f, 0.f, 0.f, 0.f};
    for (int c = 0; c < 3; ++c) {
        bf16x8 af[4];
        #pragma unroll
        for (int rt = 0; rt < 4; ++rt)
            af[rt] = *(const bf16x8*)&B1s[(rt * 16 + m) * 104 + c * 32 + qk];
        #pragma unroll
        for (int tc = 0; tc < 2; ++tc) {
            bf16x8 wfr = *(const bf16x8*)&pB1[(((w * 2 + tc) * 3 + c) * 64 + lane) * 8];
            #pragma unroll
            for (int rt = 0; rt < 4; ++rt)
                acc[rt][tc] = __builtin_amdgcn_mfma_f32_16x16x32_bf16(wfr, af[rt], acc[rt][tc], 0, 0, 0);
        }
    }
    #pragma unroll
    for (int tc = 0; tc < 2; ++tc) {
        const float4 bv = *(const float4*)&bias1[(w * 2 + tc) * 16 + q * 4];
        const float bva[4] = {bv.x, bv.y, bv.z, bv.w};
        #pragma unroll
        for (int rt = 0; rt < 4; ++rt) {
            ushort4 pk;
            float z0 = acc[rt][tc][0] + bva[0];
            float z1 = acc[rt][tc][1] + bva[1];
            float z2 = acc[rt][tc][2] + bva[2];
            float z3 = acc[rt][tc][3] + bva[3];
            if (z0 > 0.f) relumask |= 1u << (rt * 8 + tc * 4 + 0);
            if (z1 > 0.f) relumask |= 1u << (rt * 8 + tc * 4 + 1);
            if (z2 > 0.f) relumask |= 1u << (rt * 8 + tc * 4 + 2);
            if (z3 > 0.f) relumask |= 1u << (rt * 8 + tc * 4 + 3);
            pk.x = f2bf(fmaxf(z0, 0.f)); pk.y = f2bf(fmaxf(z1, 0.f));
            pk.z = f2bf(fmaxf(z2, 0.f)); pk.w = f2bf(fmaxf(z3, 0.f));
            *(ushort4*)&B0[(rt * 16 + m) * 264 + (w * 2 + tc) * 16 + q * 4] = pk;
        }
    }
    __syncthreads();                                       // (2)

    // ---- Phase C: z2 = h1 @ w2 (+b2) ; q partials ; dz2 -> B0
    #pragma unroll
    for (int tc = 0; tc < 2; ++tc)
        #pragma unroll
        for (int rt = 0; rt < 4; ++rt) acc[rt][tc] = (f32x4){0.f, 0.f, 0.f, 0.f};
    for (int c = 0; c < 8; ++c) {
        bf16x8 af[4];
        #pragma unroll
        for (int rt = 0; rt < 4; ++rt)
            af[rt] = *(const bf16x8*)&B0[(rt * 16 + m) * 264 + c * 32 + qk];
        #pragma unroll
        for (int tc = 0; tc < 2; ++tc) {
            bf16x8 wfr = *(const bf16x8*)&pB2[(((w * 2 + tc) * 8 + c) * 64 + lane) * 8];
            #pragma unroll
            for (int rt = 0; rt < 4; ++rt)
                acc[rt][tc] = __builtin_amdgcn_mfma_f32_16x16x32_bf16(wfr, af[rt], acc[rt][tc], 0, 0, 0);
        }
    }
    __syncthreads();                                       // (3)
    {
        float qp[4] = {0.f, 0.f, 0.f, 0.f};
        #pragma unroll
        for (int tc = 0; tc < 2; ++tc) {
            const float4 bv = *(const float4*)&bias2[(w * 2 + tc) * 16 + q * 4];
            const float4 wv = *(const float4*)&w3s[(w * 2 + tc) * 16 + q * 4];
            const float bva[4] = {bv.x, bv.y, bv.z, bv.w};
            const float wva[4] = {wv.x, wv.y, wv.z, wv.w};
            #pragma unroll
            for (int rt = 0; rt < 4; ++rt) {
                ushort4 pk; float dz[4];
                #pragma unroll
                for (int i = 0; i < 4; ++i) {
                    float z = acc[rt][tc][i] + bva[i];
                    if (z > 0.f) { qp[rt] += z * wva[i]; dz[i] = wva[i]; }
                    else         { dz[i] = 0.f; }
                }
                pk.x = f2bf(dz[0]); pk.y = f2bf(dz[1]);
                pk.z = f2bf(dz[2]); pk.w = f2bf(dz[3]);
                *(ushort4*)&B0[(rt * 16 + m) * 264 + (w * 2 + tc) * 16 + q * 4] = pk;
            }
        }
        #pragma unroll
        for (int rt = 0; rt < 4; ++rt) {
            float v = qp[rt];
            v += __shfl_xor(v, 16); v += __shfl_xor(v, 32);
            if (q == 0) qpart[w][rt * 16 + m] = v;
        }
    }
    __syncthreads();                                       // (4)

    if (tid < RB) {
        float qs = b3[0];
        #pragma unroll
        for (int ww = 0; ww < 8; ++ww) qs += qpart[ww][tid];
        qout[row0 + tid] = qs;
    }

    // ---- Phase D: dh1 = dz2 @ w2^T ; dz1 = dh1 * mask -> B0
    #pragma unroll
    for (int tc = 0; tc < 2; ++tc)
        #pragma unroll
        for (int rt = 0; rt < 4; ++rt) acc[rt][tc] = (f32x4){0.f, 0.f, 0.f, 0.f};
    for (int c = 0; c < 8; ++c) {
        bf16x8 af[4];
        #pragma unroll
        for (int rt = 0; rt < 4; ++rt)
            af[rt] = *(const bf16x8*)&B0[(rt * 16 + m) * 264 + c * 32 + qk];
        #pragma unroll
        for (int tc = 0; tc < 2; ++tc) {
            bf16x8 wfr = *(const bf16x8*)&pB3[(((w * 2 + tc) * 8 + c) * 64 + lane) * 8];
            #pragma unroll
            for (int rt = 0; rt < 4; ++rt)
                acc[rt][tc] = __builtin_amdgcn_mfma_f32_16x16x32_bf16(wfr, af[rt], acc[rt][tc], 0, 0, 0);
        }
    }
    __syncthreads();                                       // (5)
    #pragma unroll
    for (int rt = 0; rt < 4; ++rt)
        #pragma unroll
        for (int tc = 0; tc < 2; ++tc) {
            ushort4 pk;
            pk.x = f2bf((relumask >> (rt * 8 + tc * 4 + 0)) & 1u ? acc[rt][tc][0] : 0.f);
            pk.y = f2bf((relumask >> (rt * 8 + tc * 4 + 1)) & 1u ? acc[rt][tc][1] : 0.f);
            pk.z = f2bf((relumask >> (rt * 8 + tc * 4 + 2)) & 1u ? acc[rt][tc][2] : 0.f);
            pk.w = f2bf((relumask >> (rt * 8 + tc * 4 + 3)) & 1u ? acc[rt][tc][3] : 0.f);
            *(ushort4*)&B0[(rt * 16 + m) * 264 + (w * 2 + tc) * 16 + q * 4] = pk;
        }
    __syncthreads();                                       // (6)

    // ---- Phase E: score = dz1 @ w1[64:80]^T (waves 0..3, row-tile w)
    if (w < 4) {
        f32x4 acc2 = (f32x4){0.f, 0.f, 0.f, 0.f};
        for (int c = 0; c < 8; ++c) {
            bf16x8 af = *(const bf16x8*)&B0[(w * 16 + m) * 264 + c * 32 + qk];
            bf16x8 wfr = *(const bf16x8*)&pB4[(c * 64 + lane) * 8];
            acc2 = __builtin_amdgcn_mfma_f32_16x16x32_bf16(wfr, af, acc2, 0, 0, 0);
        }
        float4 o; o.x = acc2[0]; o.y = acc2[1]; o.z = acc2[2]; o.w = acc2[3];
        *(float4*)&score[(size_t)(row0 + w * 16 + m) * 16 + q * 4] = o;
    }
}

// ---------------------------------------------------------------------------
// SVGD update (round-6 version, verbatim — 69 us, 39% occ, 64 VGPR).
// Round-8's barrier-free wave-per-state variant used 172 VGPR -> 10.6% occ ->
// 91 us. Occupancy is the currency here; do not trade it for barriers.
// launch_bounds(256,4): 128-VGPR budget. (256,8) forced 32 VGPRs -> spill.
__global__ __launch_bounds__(256, 4) void svgd_kernel(
    const float* __restrict__ a_in,    // [BN,16]
    const float* __restrict__ score,   // [BN,16]
    const float* __restrict__ logp_in, // [BN] (ignored if first)
    float* __restrict__ logp_out,      // [BN]
    float* __restrict__ a_out,         // [BN,16]
    int first)
{
    __shared__ float X[32 * 17], S[32 * 17];
    __shared__ float D2[32 * 33], KM[32 * 33], P[32 * 33];
    __shared__ int hist[256];
    __shared__ int wsum[4];
    __shared__ int bbin, bexcl;
    __shared__ float medsh;
    __shared__ int redc[4];
    __shared__ unsigned redm[4];

    const int b = blockIdx.x, tid = threadIdx.x;
    const int lane = tid & 63, wv = tid >> 6;
    const size_t base = (size_t)b * 512;

    for (int idx = tid; idx < 512; idx += 256) {
        int r = idx >> 4, d = idx & 15;
        X[r * 17 + d] = a_in[base + idx];
        S[r * 17 + d] = score[base + idx];
    }
    __syncthreads();

    unsigned v[4];                       // this thread's 4 dist^2 values (bits)
    #pragma unroll
    for (int t = 0; t < 4; ++t) {
        int idx = tid + 256 * t, i = idx >> 5, j = idx & 31;
        float s = 0.f;
        #pragma unroll
        for (int d = 0; d < 16; ++d) {
            float df = X[i * 17 + d] - X[j * 17 + d];
            s += df * df;
        }
        D2[i * 33 + j] = s;
        v[t] = __float_as_uint(s);
    }

    // radix select: find rank-511 (0-indexed) value
    unsigned prefix = 0;
    int rank = 511;
    for (int shift = 24; shift >= 0; shift -= 8) {
        hist[tid] = 0;
        __syncthreads();
        unsigned him = (shift == 24) ? 0u : (0xFFFFFFFFu << (shift + 8));
        #pragma unroll
        for (int t = 0; t < 4; ++t)
            if ((v[t] & him) == prefix)
                atomicAdd(&hist[(v[t] >> shift) & 255], 1);
        __syncthreads();
        int c = hist[tid], inc = c;
        #pragma unroll
        for (int off = 1; off < 64; off <<= 1) {
            int tt = __shfl_up(inc, off, 64);
            if (lane >= off) inc += tt;
        }
        if (lane == 63) wsum[wv] = inc;
        __syncthreads();
        int basec = 0;
        for (int ww = 0; ww < wv; ++ww) basec += wsum[ww];
        int excl = basec + inc - c;
        if (c > 0 && rank >= excl && rank < excl + c) { bbin = tid; bexcl = excl; }
        __syncthreads();
        prefix |= ((unsigned)bbin << shift);
        rank -= bexcl;
    }
    const float v1 = __uint_as_float(prefix);

    // rank-512 value: v1 again if count(x<=v1)>=513 else min of x>v1
    {
        int cle = 0;
        unsigned mgt = 0xFFFFFFFFu;
        #pragma unroll
        for (int t = 0; t < 4; ++t) {
            if (v[t] <= prefix) cle++;
            else mgt = min(mgt, v[t]);
        }
        #pragma unroll
        for (int off = 1; off < 64; off <<= 1) {
            cle += __shfl_xor(cle, off);
            mgt = min(mgt, (unsigned)__shfl_xor((int)mgt, off));
        }
        if (lane == 0) { redc[wv] = cle; redm[wv] = mgt; }
        __syncthreads();
        if (tid == 0) {
            int C = redc[0] + redc[1] + redc[2] + redc[3];
            unsigned M = min(min(redm[0], redm[1]), min(redm[2], redm[3]));
            float v2 = (C >= 513) ? v1 : __uint_as_float(M);
            medsh = 0.5f * (v1 + v2);
        }
        __syncthreads();
    }
    const float med   = medsh;
    const float gamma = 1.0f / (2.0f * (med / LN32 + 1e-8f));

    // K and P[i][j] = sum_d diff[i,j,d] * S[j,d]
    #pragma unroll
    for (int t = 0; t < 4; ++t) {
        int idx = tid + 256 * t, i = idx >> 5, j = idx & 31;
        KM[i * 33 + j] = __expf(-gamma * __uint_as_float(v[t]));
        float p = 0.f;
        #pragma unroll
        for (int d = 0; d < 16; ++d)
            p += (X[i * 17 + d] - X[j * 17 + d]) * S[j * 17 + d];
        P[i * 33 + j] = p;
    }
    __syncthreads();

    // phi + particle update
    for (int idx = tid; idx < 512; idx += 256) {
        int i = idx >> 4, d = idx & 15;
        float s1 = 0.f, s2 = 0.f;
        float xi = X[i * 17 + d];
        #pragma unroll
        for (int j = 0; j < 32; ++j) {
            float kk = KM[i * 33 + j];
            s1 += kk * S[j * 17 + d];
            s2 += (xi - X[j * 17 + d]) * kk;
        }
        float phi = (s1 + 2.f * gamma * s2) * (1.f / 32.f);
        float av = xi + 0.1f * phi;
        av = fminf(fmaxf(av, -1.f), 1.f);
        a_out[base + idx] = av;
    }

    // logp correction (256 threads: i = tid>>3, 8 lanes reduce over j)
    {
        int i = tid >> 3, jj = tid & 7;
        float acc1 = 0.f, acc2 = 0.f;
        #pragma unroll
        for (int t = 0; t < 4; ++t) {
            int j = jj + 8 * t;
            float kk = KM[i * 33 + j];
            acc1 += kk * P[i * 33 + j];
            acc2 += (2.f * gamma * D2[i * 33 + j] - 16.f) * kk;
        }
        acc1 += __shfl_xor(acc1, 1); acc1 += __shfl_xor(acc1, 2); acc1 += __shfl_xor(acc1, 4);
        acc2 += __shfl_xor(acc2, 1); acc2 += __shfl_xor(acc2, 2); acc2 += __shfl_xor(acc2, 4);
        if (jj == 0) {
            float tmp1 = -2.f * gamma * acc1 * (1.f / 32.f);
            float tmp2 = -2.f * gamma * acc2 * (1.f / 32.f);
            float prev = first ? 0.f : logp_in[b * 32 + i];
            logp_out[b * 32 + i] = prev - 0.1f * (tmp1 + tmp2);
        }
    }
}

// ---------------------------------------------------------------------------
extern "C" void kernel_launch(void* const* d_in, const int* in_sizes, int n_in,
                              void* d_out, int out_size, void* d_ws, size_t ws_size,
                              hipStream_t stream) {
    const float* obs = (const float*)d_in[0];
    const float* a0  = (const float*)d_in[1];
    const float* w1  = (const float*)d_in[2];
    const float* b1  = (const float*)d_in[3];
    const float* w2  = (const float*)d_in[4];
    const float* b2  = (const float*)d_in[5];
    const float* w3  = (const float*)d_in[6];
    const float* b3  = (const float*)d_in[7];

    float* out_a    = (float*)d_out;                 // [BN,16]
    float* out_logp = out_a + (size_t)BNROWS * 16;   // [BN]
    float* out_q    = out_logp + BNROWS;             // [BN]

    char* p = (char*)d_ws;
    ushort* pB1 = (ushort*)p; p += 24576 * 2;
    ushort* pB2 = (ushort*)p; p += 65536 * 2;
    ushort* pB3 = (ushort*)p; p += 65536 * 2;
    ushort* pB4 = (ushort*)p; p += 4096 * 2;
    ushort* obs_bf = (ushort*)p; p += (size_t)BNROWS * 64 * 2;
    float* abuf0 = (float*)p; p += (size_t)BNROWS * 16 * 4;
    float* abuf1 = (float*)p; p += (size_t)BNROWS * 16 * 4;
    float* scr   = (float*)p; p += (size_t)BNROWS * 16 * 4;
    float* logp  = (float*)p; p += (size_t)BNROWS * 4;
    float* qtmp  = (float*)p;

    prep_pack<<<78, 256, 0, stream>>>(w1, w2, pB1, pB2, pB3, pB4);
    obs_to_bf16<<<8192, 256, 0, stream>>>(obs, obs_bf);

    const int MB = BNROWS / RB;   // 2048 blocks

    // step 1
    mlp_mfma<<<MB, 512, 0, stream>>>(obs_bf, a0, b1, b2, w3, b3,
                                     pB1, pB2, pB3, pB4, scr, qtmp);
    svgd_kernel<<<4096, 256, 0, stream>>>(a0, scr, nullptr, logp, abuf0, 1);
    // step 2
    mlp_mfma<<<MB, 512, 0, stream>>>(obs_bf, abuf0, b1, b2, w3, b3,
                                     pB1, pB2, pB3, pB4, scr, qtmp);
    svgd_kernel<<<4096, 256, 0, stream>>>(abuf0, scr, logp, logp, abuf1, 0);
    // step 3 (q of this step is the q_vals output)
    mlp_mfma<<<MB, 512, 0, stream>>>(obs_bf, abuf1, b1, b2, w3, b3,
                                     pB1, pB2, pB3, pB4, scr, out_q);
    svgd_kernel<<<4096, 256, 0, stream>>>(abuf1, scr, logp, out_logp, out_a, 0);
}

// Round 10
// 379.884 us; speedup vs baseline: 1.5055x; 1.1273x over previous
//
#include <hip/hip_runtime.h>
#include <hip/hip_bf16.h>
#include <math.h>

#define BNROWS (4096*32)   // 131072
#define RB     64          // rows per MLP block
#define LN32   3.4657359027997265f

typedef __attribute__((ext_vector_type(8))) short bf16x8;
typedef __attribute__((ext_vector_type(4))) float f32x4;

static __device__ __forceinline__ ushort f2bf(float x) {
    union { __hip_bfloat16 h; ushort u; } cv;
    cv.h = __float2bfloat16(x);
    return cv.u;
}

// ---------------------------------------------------------------------------
__global__ void obs_to_bf16(const float* __restrict__ obs,
                            ushort* __restrict__ obs_bf) {
    size_t i = ((size_t)blockIdx.x * 256 + threadIdx.x) * 4;
    float4 v = *(const float4*)&obs[i];
    ushort4 o;
    o.x = f2bf(v.x); o.y = f2bf(v.y); o.z = f2bf(v.z); o.w = f2bf(v.w);
    *(ushort4*)&obs_bf[i] = o;
}

// ---------------------------------------------------------------------------
// Pack weights into MFMA fragment order (lane-contiguous 16B loads).
// Lane (q,m): element j -> W[k = c*32 + q*8 + j][n = tile*16 + m].
__global__ void prep_pack(const float* __restrict__ w1,
                          const float* __restrict__ w2,
                          ushort* __restrict__ pB1, ushort* __restrict__ pB2,
                          ushort* __restrict__ pB3, ushort* __restrict__ pB4) {
    int g = blockIdx.x * 256 + threadIdx.x;   // 19968 total
    ushort out[8];
    ushort* dst;
    if (g < 3072) {
        int lane = g & 63, gc = g >> 6;
        int t = gc / 3, c = gc % 3;
        int m = lane & 15, q = lane >> 4, n = t * 16 + m;
        #pragma unroll
        for (int j = 0; j < 8; ++j) {
            int k = c * 32 + q * 8 + j;
            out[j] = f2bf((k < 80) ? w1[k * 256 + n] : 0.f);
        }
        dst = &pB1[g * 8];
    } else if (g < 11264) {
        int gg = g - 3072;
        int lane = gg & 63, gc = gg >> 6;
        int t = gc >> 3, c = gc & 7;
        int m = lane & 15, q = lane >> 4, n = t * 16 + m;
        #pragma unroll
        for (int j = 0; j < 8; ++j)
            out[j] = f2bf(w2[(c * 32 + q * 8 + j) * 256 + n]);
        dst = &pB2[gg * 8];
    } else if (g < 19456) {
        int gg = g - 11264;
        int lane = gg & 63, gc = gg >> 6;
        int t = gc >> 3, c = gc & 7;
        int m = lane & 15, q = lane >> 4;
        #pragma unroll
        for (int j = 0; j < 8; ++j)
            out[j] = f2bf(w2[(t * 16 + m) * 256 + c * 32 + q * 8 + j]);
        dst = &pB3[gg * 8];
    } else if (g < 19968) {
        int gg = g - 19456;
        int lane = gg & 63, c = gg >> 6;
        int m = lane & 15, q = lane >> 4;
        #pragma unroll
        for (int j = 0; j < 8; ++j)
            out[j] = f2bf(w1[(64 + m) * 256 + c * 32 + q * 8 + j]);
        dst = &pB4[gg * 8];
    } else return;
    *(uint4*)dst = *(uint4*)out;
}

// ---------------------------------------------------------------------------
// Fused critic forward + VJP, bf16 MFMA, swapped operands (round-6 layout).
// 512 threads / 8 waves, wave w owns col-tiles {2w, 2w+1} x 4 row-tiles.
// (Round-9 measured identical to the 256-thread variant -> structure-bound;
// keep as-is.) Plain __launch_bounds__: min-wave bounds spilled (r3/r4/r5).
__global__ __launch_bounds__(512) void mlp_mfma(
    const ushort* __restrict__ obs_bf,  // [BN,64] bf16
    const float* __restrict__ a_in,     // [BN,16]
    const float* __restrict__ b1,       // [256]
    const float* __restrict__ b2,       // [256]
    const float* __restrict__ w3,       // [256]
    const float* __restrict__ b3,       // [1]
    const ushort* __restrict__ pB1, const ushort* __restrict__ pB2,
    const ushort* __restrict__ pB3, const ushort* __restrict__ pB4,
    float* __restrict__ score,          // [BN,16]
    float* __restrict__ qout)           // [BN]
{
    __shared__ __align__(16) ushort B0[RB * 264];   // h1 -> dz2 -> dz1
    __shared__ __align__(16) ushort B1s[RB * 104];  // h0
    __shared__ float qpart[8][RB];
    __shared__ float bias1[256], bias2[256], w3s[256];

    const int tid  = threadIdx.x;
    const int row0 = blockIdx.x * RB;

    // ---- Phase A: stage h0 = [obs_bf16 | a->bf16 | 0pad] at stride 104
    {
        int r = tid >> 3, ch = tid & 7;                    // 512 units exactly
        *(uint4*)&B1s[r * 104 + ch * 8] =
            *(const uint4*)&obs_bf[(size_t)(row0 + r) * 64 + ch * 8];
    }
    if (tid < 256) {
        int r = tid >> 2, d0 = (tid & 3) * 4;
        float4 av = *(const float4*)&a_in[(size_t)(row0 + r) * 16 + d0];
        ushort4 pv;
        pv.x = f2bf(av.x); pv.y = f2bf(av.y); pv.z = f2bf(av.z); pv.w = f2bf(av.w);
        *(ushort4*)&B1s[r * 104 + 64 + d0] = pv;
        ushort4 zv; zv.x = zv.y = zv.z = zv.w = 0;
        *(ushort4*)&B1s[r * 104 + 80 + d0] = zv;
        bias1[tid] = b1[tid]; bias2[tid] = b2[tid]; w3s[tid] = w3[tid];
    }
    __syncthreads();                                       // (1)

    const int lane = tid & 63;
    const int w    = tid >> 6;        // wave 0..7 -> col-tiles {2w, 2w+1}
    const int m    = lane & 15;
    const int q    = lane >> 4;
    const int qk   = q * 8;

    f32x4 acc[4][2];                  // [row-tile][col-tile-in-wave]
    unsigned relumask = 0u;           // 32 bits: rt*8 + tc*4 + i

    // ---- Phase B: z1 = h0 @ w1 (+b1) ; relu -> B0 ; mask -> regs
    #pragma unroll
    for (int tc = 0; tc < 2; ++tc)
        #pragma unroll
        for (int rt = 0; rt < 4; ++rt) acc[rt][tc] = (f32x4){0.f, 0.f, 0.f, 0.f};
    for (int c = 0; c < 3; ++c) {
        bf16x8 af[4];
        #pragma unroll
        for (int rt = 0; rt < 4; ++rt)
            af[rt] = *(const bf16x8*)&B1s[(rt * 16 + m) * 104 + c * 32 + qk];
        #pragma unroll
        for (int tc = 0; tc < 2; ++tc) {
            bf16x8 wfr = *(const bf16x8*)&pB1[(((w * 2 + tc) * 3 + c) * 64 + lane) * 8];
            #pragma unroll
            for (int rt = 0; rt < 4; ++rt)
                acc[rt][tc] = __builtin_amdgcn_mfma_f32_16x16x32_bf16(wfr, af[rt], acc[rt][tc], 0, 0, 0);
        }
    }
    #pragma unroll
    for (int tc = 0; tc < 2; ++tc) {
        const float4 bv = *(const float4*)&bias1[(w * 2 + tc) * 16 + q * 4];
        const float bva[4] = {bv.x, bv.y, bv.z, bv.w};
        #pragma unroll
        for (int rt = 0; rt < 4; ++rt) {
            ushort4 pk;
            float z0 = acc[rt][tc][0] + bva[0];
            float z1 = acc[rt][tc][1] + bva[1];
            float z2 = acc[rt][tc][2] + bva[2];
            float z3 = acc[rt][tc][3] + bva[3];
            if (z0 > 0.f) relumask |= 1u << (rt * 8 + tc * 4 + 0);
            if (z1 > 0.f) relumask |= 1u << (rt * 8 + tc * 4 + 1);
            if (z2 > 0.f) relumask |= 1u << (rt * 8 + tc * 4 + 2);
            if (z3 > 0.f) relumask |= 1u << (rt * 8 + tc * 4 + 3);
            pk.x = f2bf(fmaxf(z0, 0.f)); pk.y = f2bf(fmaxf(z1, 0.f));
            pk.z = f2bf(fmaxf(z2, 0.f)); pk.w = f2bf(fmaxf(z3, 0.f));
            *(ushort4*)&B0[(rt * 16 + m) * 264 + (w * 2 + tc) * 16 + q * 4] = pk;
        }
    }
    __syncthreads();                                       // (2)

    // ---- Phase C: z2 = h1 @ w2 (+b2) ; q partials ; dz2 -> B0
    #pragma unroll
    for (int tc = 0; tc < 2; ++tc)
        #pragma unroll
        for (int rt = 0; rt < 4; ++rt) acc[rt][tc] = (f32x4){0.f, 0.f, 0.f, 0.f};
    for (int c = 0; c < 8; ++c) {
        bf16x8 af[4];
        #pragma unroll
        for (int rt = 0; rt < 4; ++rt)
            af[rt] = *(const bf16x8*)&B0[(rt * 16 + m) * 264 + c * 32 + qk];
        #pragma unroll
        for (int tc = 0; tc < 2; ++tc) {
            bf16x8 wfr = *(const bf16x8*)&pB2[(((w * 2 + tc) * 8 + c) * 64 + lane) * 8];
            #pragma unroll
            for (int rt = 0; rt < 4; ++rt)
                acc[rt][tc] = __builtin_amdgcn_mfma_f32_16x16x32_bf16(wfr, af[rt], acc[rt][tc], 0, 0, 0);
        }
    }
    __syncthreads();                                       // (3)
    {
        float qp[4] = {0.f, 0.f, 0.f, 0.f};
        #pragma unroll
        for (int tc = 0; tc < 2; ++tc) {
            const float4 bv = *(const float4*)&bias2[(w * 2 + tc) * 16 + q * 4];
            const float4 wv = *(const float4*)&w3s[(w * 2 + tc) * 16 + q * 4];
            const float bva[4] = {bv.x, bv.y, bv.z, bv.w};
            const float wva[4] = {wv.x, wv.y, wv.z, wv.w};
            #pragma unroll
            for (int rt = 0; rt < 4; ++rt) {
                ushort4 pk; float dz[4];
                #pragma unroll
                for (int i = 0; i < 4; ++i) {
                    float z = acc[rt][tc][i] + bva[i];
                    if (z > 0.f) { qp[rt] += z * wva[i]; dz[i] = wva[i]; }
                    else         { dz[i] = 0.f; }
                }
                pk.x = f2bf(dz[0]); pk.y = f2bf(dz[1]);
                pk.z = f2bf(dz[2]); pk.w = f2bf(dz[3]);
                *(ushort4*)&B0[(rt * 16 + m) * 264 + (w * 2 + tc) * 16 + q * 4] = pk;
            }
        }
        #pragma unroll
        for (int rt = 0; rt < 4; ++rt) {
            float v = qp[rt];
            v += __shfl_xor(v, 16); v += __shfl_xor(v, 32);
            if (q == 0) qpart[w][rt * 16 + m] = v;
        }
    }
    __syncthreads();                                       // (4)

    if (tid < RB) {
        float qs = b3[0];
        #pragma unroll
        for (int ww = 0; ww < 8; ++ww) qs += qpart[ww][tid];
        qout[row0 + tid] = qs;
    }

    // ---- Phase D: dh1 = dz2 @ w2^T ; dz1 = dh1 * mask -> B0
    #pragma unroll
    for (int tc = 0; tc < 2; ++tc)
        #pragma unroll
        for (int rt = 0; rt < 4; ++rt) acc[rt][tc] = (f32x4){0.f, 0.f, 0.f, 0.f};
    for (int c = 0; c < 8; ++c) {
        bf16x8 af[4];
        #pragma unroll
        for (int rt = 0; rt < 4; ++rt)
            af[rt] = *(const bf16x8*)&B0[(rt * 16 + m) * 264 + c * 32 + qk];
        #pragma unroll
        for (int tc = 0; tc < 2; ++tc) {
            bf16x8 wfr = *(const bf16x8*)&pB3[(((w * 2 + tc) * 8 + c) * 64 + lane) * 8];
            #pragma unroll
            for (int rt = 0; rt < 4; ++rt)
                acc[rt][tc] = __builtin_amdgcn_mfma_f32_16x16x32_bf16(wfr, af[rt], acc[rt][tc], 0, 0, 0);
        }
    }
    __syncthreads();                                       // (5)
    #pragma unroll
    for (int rt = 0; rt < 4; ++rt)
        #pragma unroll
        for (int tc = 0; tc < 2; ++tc) {
            ushort4 pk;
            pk.x = f2bf((relumask >> (rt * 8 + tc * 4 + 0)) & 1u ? acc[rt][tc][0] : 0.f);
            pk.y = f2bf((relumask >> (rt * 8 + tc * 4 + 1)) & 1u ? acc[rt][tc][1] : 0.f);
            pk.z = f2bf((relumask >> (rt * 8 + tc * 4 + 2)) & 1u ? acc[rt][tc][2] : 0.f);
            pk.w = f2bf((relumask >> (rt * 8 + tc * 4 + 3)) & 1u ? acc[rt][tc][3] : 0.f);
            *(ushort4*)&B0[(rt * 16 + m) * 264 + (w * 2 + tc) * 16 + q * 4] = pk;
        }
    __syncthreads();                                       // (6)

    // ---- Phase E: score = dz1 @ w1[64:80]^T (waves 0..3, row-tile w)
    if (w < 4) {
        f32x4 acc2 = (f32x4){0.f, 0.f, 0.f, 0.f};
        for (int c = 0; c < 8; ++c) {
            bf16x8 af = *(const bf16x8*)&B0[(w * 16 + m) * 264 + c * 32 + qk];
            bf16x8 wfr = *(const bf16x8*)&pB4[(c * 64 + lane) * 8];
            acc2 = __builtin_amdgcn_mfma_f32_16x16x32_bf16(wfr, af, acc2, 0, 0, 0);
        }
        float4 o; o.x = acc2[0]; o.y = acc2[1]; o.z = acc2[2]; o.w = acc2[3];
        *(float4*)&score[(size_t)(row0 + w * 16 + m) * 16 + q * 4] = o;
    }
}

// ---------------------------------------------------------------------------
// SVGD v3 (round-10): one block per state, 256 thr / 4 waves as round-6, plus:
//  - P fused into the dist loop (registers) — KP phase X/S re-reads gone
//  - logp computed entirely from registers via 32-lane shfl butterfly
//    (D2/P LDS arrays deleted; the old i=tid>>3 mapping had ~8-way conflicts)
//  - 3-pass radix select (11/11/10 bits, 2048-bin hist): 12 barriers vs 16,
//    collisions spread over 8x more bins. Still bit-exact jnp.median.
//  - KM stride 40 (banks (8i+j)&31: conflict-free writes, broadcast phi reads)
// launch_bounds(256,4): 128-VGPR budget. (256,8) forced 32 VGPRs -> spill (r3).
// Occupancy is the currency (r8: 172-VGPR barrier-free variant -> 91 us).
__global__ __launch_bounds__(256, 4) void svgd_kernel(
    const float* __restrict__ a_in,    // [BN,16]
    const float* __restrict__ score,   // [BN,16]
    const float* __restrict__ logp_in, // [BN] (ignored if first)
    float* __restrict__ logp_out,      // [BN]
    float* __restrict__ a_out,         // [BN,16]
    int first)
{
    __shared__ float X[32 * 17], S[32 * 17];
    __shared__ float KM[32 * 40];
    __shared__ int hist[2048];
    __shared__ int wsum[4];
    __shared__ int bbin, bexcl;
    __shared__ int redc[4];
    __shared__ unsigned redm[4];

    const int b = blockIdx.x, tid = threadIdx.x;
    const int lane = tid & 63, wv = tid >> 6;
    const size_t base = (size_t)b * 512;

    for (int idx = tid; idx < 512; idx += 256) {
        int r = idx >> 4, d = idx & 15;
        X[r * 17 + d] = a_in[base + idx];
        S[r * 17 + d] = score[base + idx];
    }
    __syncthreads();

    // dist^2 (bits) and P fused; thread owns pairs (i = tid>>5 + 8t, j = tid&31)
    unsigned v[4]; float p[4];
    #pragma unroll
    for (int t = 0; t < 4; ++t) {
        int idx = tid + 256 * t, i = idx >> 5, j = idx & 31;
        float s = 0.f, pp = 0.f;
        #pragma unroll
        for (int d = 0; d < 16; ++d) {
            float df = X[i * 17 + d] - X[j * 17 + d];
            s  = fmaf(df, df, s);
            pp = fmaf(df, S[j * 17 + d], pp);
        }
        v[t] = __float_as_uint(s);
        p[t] = pp;
    }

    // ---- 3-pass radix select: rank-511 value (bit-exact)
    unsigned prefix = 0;
    int rank = 511;
    #pragma unroll
    for (int pass = 0; pass < 3; ++pass) {
        const int sh = (pass == 0) ? 21 : (pass == 1) ? 10 : 0;
        const unsigned dmask = (pass == 2) ? 1023u : 2047u;
        #pragma unroll
        for (int k = 0; k < 8; ++k) hist[tid + 256 * k] = 0;
        __syncthreads();
        #pragma unroll
        for (int t = 0; t < 4; ++t) {
            bool ok = (pass == 0) ||
                      ((v[t] >> (sh + ((pass == 1) ? 11 : 10))) == prefix);
            if (ok) atomicAdd(&hist[(v[t] >> sh) & dmask], 1);
        }
        __syncthreads();
        int c[8], ct = 0;
        #pragma unroll
        for (int k = 0; k < 8; ++k) { c[k] = hist[8 * tid + k]; ct += c[k]; }
        int inc = ct;
        #pragma unroll
        for (int off = 1; off < 64; off <<= 1) {
            int tt = __shfl_up(inc, off, 64);
            if (lane >= off) inc += tt;
        }
        if (lane == 63) wsum[wv] = inc;
        __syncthreads();
        int run = inc - ct;
        for (int ww = 0; ww < wv; ++ww) run += wsum[ww];
        #pragma unroll
        for (int k = 0; k < 8; ++k) {
            if (c[k] > 0 && rank >= run && rank < run + c[k]) {
                bbin = 8 * tid + k; bexcl = run;
            }
            run += c[k];
        }
        __syncthreads();
        prefix = (prefix << ((pass == 2) ? 10 : 11)) | (unsigned)bbin;
        rank -= bexcl;
    }
    const float v1 = __uint_as_float(prefix);

    // rank-512 value: v1 again if count(x<=v1)>=513 else min of x>v1
    float med;
    {
        int cle = 0;
        unsigned mgt = 0xFFFFFFFFu;
        #pragma unroll
        for (int t = 0; t < 4; ++t) {
            if (v[t] <= prefix) cle++;
            else mgt = min(mgt, v[t]);
        }
        #pragma unroll
        for (int off = 1; off < 64; off <<= 1) {
            cle += __shfl_xor(cle, off);
            mgt = min(mgt, (unsigned)__shfl_xor((int)mgt, off));
        }
        if (lane == 0) { redc[wv] = cle; redm[wv] = mgt; }
        __syncthreads();
        int C = redc[0] + redc[1] + redc[2] + redc[3];
        unsigned M = min(min(redm[0], redm[1]), min(redm[2], redm[3]));
        float v2 = (C >= 513) ? v1 : __uint_as_float(M);
        med = 0.5f * (v1 + v2);
    }
    const float gamma = 1.0f / (2.0f * (med / LN32 + 1e-8f));

    // ---- K: registers + LDS (stride 40; write banks (8i+j)&31 distinct)
    float kreg[4];
    #pragma unroll
    for (int t = 0; t < 4; ++t) {
        int idx = tid + 256 * t, i = idx >> 5, j = idx & 31;
        float kk = __expf(-gamma * __uint_as_float(v[t]));
        kreg[t] = kk;
        KM[i * 40 + j] = kk;
    }

    // ---- logp from registers (no LDS, no barrier): butterfly over j=lane&31
    {
        float acc1[4], acc2[4];
        #pragma unroll
        for (int t = 0; t < 4; ++t) {
            float a1 = kreg[t] * p[t];
            float a2 = (2.f * gamma * __uint_as_float(v[t]) - 16.f) * kreg[t];
            #pragma unroll
            for (int off = 1; off < 32; off <<= 1) {
                a1 += __shfl_xor(a1, off);
                a2 += __shfl_xor(a2, off);
            }
            acc1[t] = a1; acc2[t] = a2;
        }
        if ((tid & 31) == 0) {
            #pragma unroll
            for (int t = 0; t < 4; ++t) {
                int i = (tid >> 5) + 8 * t;
                float tmp = -2.f * gamma * (acc1[t] + acc2[t]) * (1.f / 32.f);
                float prev = first ? 0.f : logp_in[b * 32 + i];
                logp_out[b * 32 + i] = prev - 0.1f * tmp;
            }
        }
    }
    __syncthreads();                   // KM visible for phi

    // ---- phi + particle update
    for (int idx = tid; idx < 512; idx += 256) {
        int i = idx >> 4, d = idx & 15;
        float s1 = 0.f, s2 = 0.f;
        float xi = X[i * 17 + d];
        #pragma unroll
        for (int j = 0; j < 32; ++j) {
            float kk = KM[i * 40 + j];
            s1 = fmaf(kk, S[j * 17 + d], s1);
            s2 = fmaf(kk, xi - X[j * 17 + d], s2);
        }
        float phi = (s1 + 2.f * gamma * s2) * (1.f / 32.f);
        float av = xi + 0.1f * phi;
        av = fminf(fmaxf(av, -1.f), 1.f);
        a_out[base + idx] = av;
    }
}

// ---------------------------------------------------------------------------
extern "C" void kernel_launch(void* const* d_in, const int* in_sizes, int n_in,
                              void* d_out, int out_size, void* d_ws, size_t ws_size,
                              hipStream_t stream) {
    const float* obs = (const float*)d_in[0];
    const float* a0  = (const float*)d_in[1];
    const float* w1  = (const float*)d_in[2];
    const float* b1  = (const float*)d_in[3];
    const float* w2  = (const float*)d_in[4];
    const float* b2  = (const float*)d_in[5];
    const float* w3  = (const float*)d_in[6];
    const float* b3  = (const float*)d_in[7];

    float* out_a    = (float*)d_out;                 // [BN,16]
    float* out_logp = out_a + (size_t)BNROWS * 16;   // [BN]
    float* out_q    = out_logp + BNROWS;             // [BN]

    char* p = (char*)d_ws;
    ushort* pB1 = (ushort*)p; p += 24576 * 2;
    ushort* pB2 = (ushort*)p; p += 65536 * 2;
    ushort* pB3 = (ushort*)p; p += 65536 * 2;
    ushort* pB4 = (ushort*)p; p += 4096 * 2;
    ushort* obs_bf = (ushort*)p; p += (size_t)BNROWS * 64 * 2;
    float* abuf0 = (float*)p; p += (size_t)BNROWS * 16 * 4;
    float* abuf1 = (float*)p; p += (size_t)BNROWS * 16 * 4;
    float* scr   = (float*)p; p += (size_t)BNROWS * 16 * 4;
    float* logp  = (float*)p; p += (size_t)BNROWS * 4;
    float* qtmp  = (float*)p;

    prep_pack<<<78, 256, 0, stream>>>(w1, w2, pB1, pB2, pB3, pB4);
    obs_to_bf16<<<8192, 256, 0, stream>>>(obs, obs_bf);

    const int MB = BNROWS / RB;   // 2048 blocks

    // step 1
    mlp_mfma<<<MB, 512, 0, stream>>>(obs_bf, a0, b1, b2, w3, b3,
                                     pB1, pB2, pB3, pB4, scr, qtmp);
    svgd_kernel<<<4096, 256, 0, stream>>>(a0, scr, nullptr, logp, abuf0, 1);
    // step 2
    mlp_mfma<<<MB, 512, 0, stream>>>(obs_bf, abuf0, b1, b2, w3, b3,
                                     pB1, pB2, pB3, pB4, scr, qtmp);
    svgd_kernel<<<4096, 256, 0, stream>>>(abuf0, scr, logp, logp, abuf1, 0);
    // step 3 (q of this step is the q_vals output)
    mlp_mfma<<<MB, 512, 0, stream>>>(obs_bf, abuf1, b1, b2, w3, b3,
                                     pB1, pB2, pB3, pB4, scr, out_q);
    svgd_kernel<<<4096, 256, 0, stream>>>(abuf1, scr, logp, out_logp, out_a, 0);
}